// Round 3
// baseline (893.768 us; speedup 1.0000x reference)
//
#include <hip/hip_runtime.h>

#define BN 32            // rows per block
#define DC 16            // d-chunk
#define WSP 516          // padded LDS stride for ws (floats): 516*4B % 16 == 0
#define QSP 260          // padded LDS stride for qs (floats): 260*4B % 16 == 0

static constexpr int       Dn     = 256;
static constexpr int       Kn     = 512;
static constexpr long long NROWS  = 65536;        // 16*64*64
static constexpr long long QELEMS = 16777216LL;   // 16*256*64*64
static constexpr long long EELEMS = 33554432LL;   // 65536*512

// ---------------- w2[k] = sum_d w[k][d]^2 ----------------
__global__ __launch_bounds__(64) void w2_kernel(const float* __restrict__ w,
                                                float* __restrict__ w2) {
    const int k = blockIdx.x;
    const int l = threadIdx.x;
    const float4 v = *reinterpret_cast<const float4*>(w + (long long)k * Dn + l * 4);
    float s = fmaf(v.x, v.x, fmaf(v.y, v.y, fmaf(v.z, v.z, v.w * v.w)));
    #pragma unroll
    for (int o = 32; o > 0; o >>= 1) s += __shfl_down(s, o, 64);
    if (l == 0) w2[k] = s;
}

// ---------------- main: distances + argmin + all outputs ----------------
// Thread mapping (compute phase): cg = t&31, rg = t>>5.
//   rowgroup = rg>>1 (0..3) -> rows rowgroup*8 .. +7   (8 rows/thread)
//   half     = rg&1         -> codes half*256 + p*128 + cg*4 + q  (8 codes/thread)
// Every w ds_read_b128 is lane-dense (16B consecutive across cg) -> conflict-free.
// Every x ds_read_b128 is a full-wave broadcast (wave shares rowgroup) -> ~free.
__global__ __launch_bounds__(256) void vq_main(const float* __restrict__ x,
                                               const float* __restrict__ w,
                                               const float* __restrict__ w2,
                                               float* __restrict__ out,
                                               double* __restrict__ lsum) {
    __shared__ union {
        struct {
            float ws[DC][WSP];   // transposed weight chunk: ws[d][k]
            float xs[DC][BN];    // x chunk: xs[d][r]
        } c;
        struct {
            float qs[BN][QSP];   // selected code rows for epilogue
        } e;
    } sm;
    __shared__ float x2s[BN];
    __shared__ unsigned long long best[BN];
    __shared__ int kwin_s[BN];
    __shared__ float w2s[Kn];

    const int t   = threadIdx.x;
    const int n0  = blockIdx.x * BN;
    const int b   = n0 >> 12;            // 4096 rows per batch image
    const int hw0 = n0 & 4095;
    const long long xbase = (long long)b * 1048576 + hw0;

    if (t < BN) best[t] = ~0ULL;
    w2s[t]       = w2[t];
    w2s[t + 256] = w2[t + 256];

    const int cg    = t & 31;
    const int rg    = t >> 5;
    const int rowg  = rg >> 1;           // 0..3
    const int half  = rg & 1;            // 0..1
    const int kbase = half * 256 + cg * 4;

    float acc[8][8];
    #pragma unroll
    for (int i = 0; i < 8; ++i)
        #pragma unroll
        for (int j = 0; j < 8; ++j) acc[i][j] = 0.f;

    float x2loc = 0.f;                   // only meaningful for t < 32
    const int dd0 = t >> 5, rr = t & 31;

    for (int c = 0; c < Dn / DC; ++c) {
        const int d0 = c * DC;
        // stage x chunk (coalesced 128B per 32 lanes)
        sm.c.xs[dd0][rr]     = x[xbase + (long long)(d0 + dd0) * 4096 + rr];
        sm.c.xs[dd0 + 8][rr] = x[xbase + (long long)(d0 + dd0 + 8) * 4096 + rr];
        // stage weight chunk transposed (L2-resident reads, float4)
        #pragma unroll
        for (int kk = t; kk < Kn; kk += 256) {
            const long long wb = (long long)kk * Dn + d0;
            const float4 a0 = *reinterpret_cast<const float4*>(w + wb);
            const float4 a1 = *reinterpret_cast<const float4*>(w + wb + 4);
            const float4 a2 = *reinterpret_cast<const float4*>(w + wb + 8);
            const float4 a3 = *reinterpret_cast<const float4*>(w + wb + 12);
            sm.c.ws[0][kk]  = a0.x; sm.c.ws[1][kk]  = a0.y;
            sm.c.ws[2][kk]  = a0.z; sm.c.ws[3][kk]  = a0.w;
            sm.c.ws[4][kk]  = a1.x; sm.c.ws[5][kk]  = a1.y;
            sm.c.ws[6][kk]  = a1.z; sm.c.ws[7][kk]  = a1.w;
            sm.c.ws[8][kk]  = a2.x; sm.c.ws[9][kk]  = a2.y;
            sm.c.ws[10][kk] = a2.z; sm.c.ws[11][kk] = a2.w;
            sm.c.ws[12][kk] = a3.x; sm.c.ws[13][kk] = a3.y;
            sm.c.ws[14][kk] = a3.z; sm.c.ws[15][kk] = a3.w;
        }
        __syncthreads();
        if (t < BN) {                    // ||x_r||^2, 2-level (chunked) summation
            float p = 0.f;
            #pragma unroll
            for (int dd = 0; dd < DC; ++dd) {
                const float v = sm.c.xs[dd][t];
                p = fmaf(v, v, p);
            }
            x2loc += p;
        }
        #pragma unroll
        for (int dd = 0; dd < DC; ++dd) {
            const float4 xv0 = *reinterpret_cast<const float4*>(&sm.c.xs[dd][rowg * 8]);
            const float4 xv1 = *reinterpret_cast<const float4*>(&sm.c.xs[dd][rowg * 8 + 4]);
            const float4 wv0 = *reinterpret_cast<const float4*>(&sm.c.ws[dd][kbase]);
            const float4 wv1 = *reinterpret_cast<const float4*>(&sm.c.ws[dd][kbase + 128]);
            const float xr[8] = {xv0.x, xv0.y, xv0.z, xv0.w, xv1.x, xv1.y, xv1.z, xv1.w};
            const float wr[8] = {wv0.x, wv0.y, wv0.z, wv0.w, wv1.x, wv1.y, wv1.z, wv1.w};
            #pragma unroll
            for (int i = 0; i < 8; ++i)
                #pragma unroll
                for (int j = 0; j < 8; ++j)
                    acc[i][j] = fmaf(xr[i], wr[j], acc[i][j]);
        }
        __syncthreads();
    }

    if (t < BN) x2s[t] = x2loc;
    __syncthreads();

    // ---- argmin with reference-matching formula & first-index tie-break ----
    #pragma unroll
    for (int i = 0; i < 8; ++i) {
        const int r = rowg * 8 + i;
        const float s = x2s[r];
        unsigned long long mb = ~0ULL;
        #pragma unroll
        for (int j = 0; j < 8; ++j) {
            const int k = kbase + (j >> 2) * 128 + (j & 3);
            const float dist = (s + w2s[k]) - 2.0f * acc[i][j];   // positive => bit-monotone
            const unsigned long long p =
                ((unsigned long long)__float_as_uint(dist) << 32) | (unsigned)k;
            mb = p < mb ? p : mb;
        }
        atomicMin(&best[r], mb);
    }
    __syncthreads();

    if (t < BN) {
        const unsigned kw = (unsigned)best[t];
        kwin_s[t] = (int)kw;
        out[1 + QELEMS + EELEMS + n0 + t] = (float)kw;   // idx as float
    }
    __syncthreads();

    // ---- stage winning code rows into LDS ----
    {
        const int r = t >> 3, l8 = t & 7;
        const int kw = kwin_s[r];
        #pragma unroll
        for (int j = 0; j < 8; ++j) {
            const float4 v = *reinterpret_cast<const float4*>(
                w + (long long)kw * Dn + (l8 + 8 * j) * 4);
            *reinterpret_cast<float4*>(&sm.e.qs[r][(l8 + 8 * j) * 4]) = v;
        }
    }
    __syncthreads();

    // ---- encodings (one-hot), fully coalesced scalar stores ----
    {
        float* ebase = out + 1 + QELEMS + (long long)n0 * Kn;
        #pragma unroll
        for (int j = 0; j < 64; ++j) {
            const int f = t + 256 * j;          // 0..16383
            const int r = f >> 9, col = f & 511;
            ebase[f] = (col == kwin_s[r]) ? 1.0f : 0.0f;
        }
    }

    // ---- quantized_st + loss ----
    float part = 0.f;
    {
        const int r = t & 31, dcol = t >> 5;
        #pragma unroll
        for (int i = 0; i < 32; ++i) {
            const int d = dcol + 8 * i;
            const float q = sm.e.qs[r][d];
            const long long off = xbase + (long long)d * 4096 + r;
            const float xv = x[off];
            out[1 + off] = xv + (q - xv);       // exact stop-gradient arithmetic
            const float diff = q - xv;
            part = fmaf(diff, diff, part);
        }
    }
    #pragma unroll
    for (int o = 32; o > 0; o >>= 1) part += __shfl_down(part, o, 64);
    if ((t & 63) == 0) atomicAdd(lsum, (double)part);
}

// ---------------- finalize loss ----------------
__global__ __launch_bounds__(64) void fin_kernel(const double* __restrict__ lsum,
                                                 float* __restrict__ out) {
    if (threadIdx.x == 0) {
        const float m = (float)(*lsum / (double)QELEMS);  // mean((q-x)^2)
        out[0] = m + m;                                   // vq_loss + commit_loss
    }
}

extern "C" void kernel_launch(void* const* d_in, const int* in_sizes, int n_in,
                              void* d_out, int out_size, void* d_ws, size_t ws_size,
                              hipStream_t stream) {
    const float* x = (const float*)d_in[0];
    const float* w = (const float*)d_in[1];
    float* out  = (float*)d_out;
    double* lsum = (double*)d_ws;
    float* w2   = (float*)((char*)d_ws + 16);

    hipMemsetAsync(d_ws, 0, 16, stream);
    hipLaunchKernelGGL(w2_kernel, dim3(Kn), dim3(64), 0, stream, w, w2);
    hipLaunchKernelGGL(vq_main, dim3((int)(NROWS / BN)), dim3(256), 0, stream,
                       x, w, w2, out, lsum);
    hipLaunchKernelGGL(fin_kernel, dim3(1), dim3(1), 0, stream, lsum, out);
}

// Round 6
// 447.562 us; speedup vs baseline: 1.9970x; 1.9970x over previous
//
#include <hip/hip_runtime.h>

typedef short bf16x8 __attribute__((ext_vector_type(8)));
typedef float f32x4  __attribute__((ext_vector_type(4)));

static constexpr int       Dn     = 256;
static constexpr int       Kn     = 512;
static constexpr long long NROWS  = 65536;        // 16*64*64
static constexpr long long QELEMS = 16777216LL;   // 16*256*64*64
static constexpr long long EELEMS = 33554432LL;   // 65536*512

#define BN   64        // rows per block
#define EPSW 0.010f    // screen window > worst-case 2x bf16 screen error (~8e-3)
#define MAXC 16        // candidate slots per row

__device__ __forceinline__ unsigned short f2bf(float f) {   // RNE f32->bf16
    unsigned u = __float_as_uint(f);
    u += 0x7FFFu + ((u >> 16) & 1u);
    return (unsigned short)(u >> 16);
}

// ---------------- prep: w2[k] (EXACT round-3 arithmetic) + w -> bf16 ----------------
__global__ __launch_bounds__(64) void prep_kernel(const float* __restrict__ w,
                                                  float* __restrict__ w2,
                                                  unsigned short* __restrict__ wbf) {
    const int k = blockIdx.x;
    const int l = threadIdx.x;
    const float4 v = *reinterpret_cast<const float4*>(w + (long long)k * Dn + l * 4);
    float s = fmaf(v.x, v.x, fmaf(v.y, v.y, fmaf(v.z, v.z, v.w * v.w)));
    #pragma unroll
    for (int o = 32; o > 0; o >>= 1) s += __shfl_down(s, o, 64);
    if (l == 0) w2[k] = s;
    ushort4 b;
    b.x = f2bf(v.x); b.y = f2bf(v.y); b.z = f2bf(v.z); b.w = f2bf(v.w);
    *reinterpret_cast<ushort4*>(wbf + (long long)k * Dn + l * 4) = b;
}

// ---------------- main: MFMA screen -> exact fp32 rescore -> outputs ----------------
__global__ __launch_bounds__(256) void vq_main(const float* __restrict__ x,
                                               const float* __restrict__ w,
                                               const float* __restrict__ w2,
                                               const unsigned short* __restrict__ wbf,
                                               float* __restrict__ out,
                                               double* __restrict__ lsum) {
    __shared__ __align__(16) unsigned short xb[BN * 256];   // 32 KiB swizzled bf16 x tile
    __shared__ float w2s[Kn];
    __shared__ float partial[4][BN];
    __shared__ float mEps[BN];
    __shared__ int   ccnt[BN];
    __shared__ unsigned short cand[BN][MAXC];
    __shared__ unsigned long long best[BN];
    __shared__ int   kwin[BN];

    const int t  = threadIdx.x;
    const int wv = t >> 6;                 // wave 0..3
    const int ln = t & 63;                 // lane 0..63
    const int n0 = blockIdx.x * BN;
    const long long xbase = (long long)(n0 >> 12) * 1048576LL + (n0 & 4095);

    w2s[t]       = w2[t];
    w2s[t + 256] = w2[t + 256];
    if (t < BN) { ccnt[t] = 0; best[t] = ~0ULL; }

    // ---- stage x tile -> bf16 LDS, XOR-swizzled (16B units within 128B groups) ----
    {
        const int r = ln;                  // lanes contiguous in r -> coalesced global loads
        #pragma unroll
        for (int i = 0; i < 8; ++i) {
            const int ublk = wv * 8 + i;   // 16B unit index 0..31 (d = ublk*8..+7)
            const int d0 = ublk * 8;
            unsigned short e[8];
            #pragma unroll
            for (int j = 0; j < 8; ++j)
                e[j] = f2bf(x[xbase + (long long)(d0 + j) * 4096 + r]);
            uint4 pk;
            pk.x = (unsigned)e[0] | ((unsigned)e[1] << 16);
            pk.y = (unsigned)e[2] | ((unsigned)e[3] << 16);
            pk.z = (unsigned)e[4] | ((unsigned)e[5] << 16);
            pk.w = (unsigned)e[6] | ((unsigned)e[7] << 16);
            const int up = ublk ^ (r & 7);
            *reinterpret_cast<uint4*>(&xb[r * 256 + up * 8]) = pk;
        }
    }
    __syncthreads();

    // ---- MFMA screen: S[64 rows][512 codes] bf16, codes split across waves ----
    const int wb = wv * 128;               // this wave's code base
    const int lm = ln & 15;
    const int ls = ln >> 4;

    f32x4 acc[4][8];                       // [row-tile][code-tile]
    #pragma unroll
    for (int rt = 0; rt < 4; ++rt)
        #pragma unroll
        for (int ct = 0; ct < 8; ++ct)
            acc[rt][ct] = (f32x4){0.f, 0.f, 0.f, 0.f};

    #pragma unroll
    for (int kc = 0; kc < 8; ++kc) {
        bf16x8 af[4];
        #pragma unroll
        for (int rt = 0; rt < 4; ++rt) {   // A frag: row = lm, k = kc*32 + ls*8 + j
            const int row = rt * 16 + lm;
            const int up  = (kc * 4 + ls) ^ (row & 7);
            af[rt] = *reinterpret_cast<const bf16x8*>(&xb[row * 256 + up * 8]);
        }
        #pragma unroll
        for (int ct = 0; ct < 8; ++ct) {   // B frag direct from global (L2-hot)
            const int code = wb + ct * 16 + lm;
            const bf16x8 bf = *reinterpret_cast<const bf16x8*>(
                wbf + (long long)code * 256 + kc * 32 + ls * 8);
            #pragma unroll
            for (int rt = 0; rt < 4; ++rt)
                acc[rt][ct] = __builtin_amdgcn_mfma_f32_16x16x32_bf16(af[rt], bf, acc[rt][ct], 0, 0, 0);
        }
    }

    // ---- per-row approx min of v = w2[k] - 2*dot  (C layout: row=ls*4+rg, col=lm) ----
    float vmin[4][4];
    #pragma unroll
    for (int rt = 0; rt < 4; ++rt)
        #pragma unroll
        for (int rg = 0; rg < 4; ++rg) vmin[rt][rg] = 3.0e38f;
    #pragma unroll
    for (int ct = 0; ct < 8; ++ct) {
        const float w2k = w2s[wb + ct * 16 + lm];
        #pragma unroll
        for (int rt = 0; rt < 4; ++rt)
            #pragma unroll
            for (int rg = 0; rg < 4; ++rg)
                vmin[rt][rg] = fminf(vmin[rt][rg], fmaf(-2.0f, acc[rt][ct][rg], w2k));
    }
    #pragma unroll
    for (int o = 1; o <= 8; o <<= 1)
        #pragma unroll
        for (int rt = 0; rt < 4; ++rt)
            #pragma unroll
            for (int rg = 0; rg < 4; ++rg)
                vmin[rt][rg] = fminf(vmin[rt][rg], __shfl_xor(vmin[rt][rg], o, 64));
    if (lm == 0) {
        #pragma unroll
        for (int rt = 0; rt < 4; ++rt)
            #pragma unroll
            for (int rg = 0; rg < 4; ++rg)
                partial[wv][rt * 16 + ls * 4 + rg] = vmin[rt][rg];
    }
    __syncthreads();
    if (t < BN)
        mEps[t] = fminf(fminf(partial[0][t], partial[1][t]),
                        fminf(partial[2][t], partial[3][t])) + EPSW;
    __syncthreads();

    // ---- candidate collection: every code within EPS of approx min ----
    #pragma unroll
    for (int ct = 0; ct < 8; ++ct) {
        const float w2k = w2s[wb + ct * 16 + lm];
        #pragma unroll
        for (int rt = 0; rt < 4; ++rt)
            #pragma unroll
            for (int rg = 0; rg < 4; ++rg) {
                const float v = fmaf(-2.0f, acc[rt][ct][rg], w2k);
                const int row = rt * 16 + ls * 4 + rg;
                if (v <= mEps[row]) {
                    const int slot = atomicAdd(&ccnt[row], 1);
                    if (slot < MAXC) cand[row][slot] = (unsigned short)(wb + ct * 16 + lm);
                }
            }
    }
    __syncthreads();

    // ---- exact fp32 rescore: bit-identical to round-3 arithmetic ----
    {
        const int r  = ln;
        const int nc = min(ccnt[r], MAXC);
        const int k0 = (wv      < nc) ? (int)cand[r][wv]      : -1;
        const int k1 = (wv + 4  < nc) ? (int)cand[r][wv + 4]  : -1;
        const int k2 = (wv + 8  < nc) ? (int)cand[r][wv + 8]  : -1;
        const int k3 = (wv + 12 < nc) ? (int)cand[r][wv + 12] : -1;
        if (__any(k0 >= 0)) {
            const float* __restrict__ xp  = x + xbase + r;
            const float* __restrict__ wp0 = w + (long long)(k0 < 0 ? 0 : k0) * Dn;
            const float* __restrict__ wp1 = w + (long long)(k1 < 0 ? 0 : k1) * Dn;
            const float* __restrict__ wp2 = w + (long long)(k2 < 0 ? 0 : k2) * Dn;
            const float* __restrict__ wp3 = w + (long long)(k3 < 0 ? 0 : k3) * Dn;
            float s = 0.f, dot0 = 0.f, dot1 = 0.f, dot2 = 0.f, dot3 = 0.f;
            for (int c = 0; c < 16; ++c) {         // EXACT round-3 two-level ||x||^2
                float p = 0.f;
                #pragma unroll
                for (int dd = 0; dd < 16; ++dd) {
                    const int d = c * 16 + dd;     // sequential-d fmaf: round-3 dot order
                    const float xv = xp[(long long)d * 4096];
                    p = fmaf(xv, xv, p);
                    dot0 = fmaf(xv, wp0[d], dot0);
                    dot1 = fmaf(xv, wp1[d], dot1);
                    dot2 = fmaf(xv, wp2[d], dot2);
                    dot3 = fmaf(xv, wp3[d], dot3);
                }
                s += p;
            }
            if (k0 >= 0) { const float dist = (s + w2s[k0]) - 2.0f * dot0;
                atomicMin(&best[r], ((unsigned long long)__float_as_uint(dist) << 32) | (unsigned)k0); }
            if (k1 >= 0) { const float dist = (s + w2s[k1]) - 2.0f * dot1;
                atomicMin(&best[r], ((unsigned long long)__float_as_uint(dist) << 32) | (unsigned)k1); }
            if (k2 >= 0) { const float dist = (s + w2s[k2]) - 2.0f * dot2;
                atomicMin(&best[r], ((unsigned long long)__float_as_uint(dist) << 32) | (unsigned)k2); }
            if (k3 >= 0) { const float dist = (s + w2s[k3]) - 2.0f * dot3;
                atomicMin(&best[r], ((unsigned long long)__float_as_uint(dist) << 32) | (unsigned)k3); }
        }
    }
    __syncthreads();

    if (t < BN) {
        const unsigned kw = (unsigned)best[t];
        kwin[t] = (int)kw;
        out[1 + QELEMS + EELEMS + n0 + t] = (float)kw;     // idx as float
    }
    __syncthreads();

    // ---- encodings (one-hot), coalesced ----
    {
        float* __restrict__ ebase = out + 1 + QELEMS + (long long)n0 * Kn;
        #pragma unroll 4
        for (int j = 0; j < 128; ++j) {
            const int f = t + 256 * j;                     // 0..32767
            const int row = f >> 9, col = f & 511;
            ebase[f] = (col == kwin[row]) ? 1.0f : 0.0f;
        }
    }

    // ---- quantized_st + loss ----
    {
        const int r = ln;                                  // lanes contiguous in r
        const float* __restrict__ wrow = w + (long long)kwin[r] * Dn;
        float part = 0.f;
        #pragma unroll 8
        for (int i = 0; i < 64; ++i) {
            const int d = wv * 64 + i;
            const long long off = xbase + (long long)d * 4096 + r;
            const float xv = x[off];
            const float q  = wrow[d];
            out[1 + off] = xv + (q - xv);                  // exact stop-gradient arithmetic
            const float diff = q - xv;
            part = fmaf(diff, diff, part);
        }
        #pragma unroll
        for (int o = 32; o > 0; o >>= 1) part += __shfl_down(part, o, 64);
        if (ln == 0) atomicAdd(lsum, (double)part);
    }
}

// ---------------- finalize loss ----------------
__global__ __launch_bounds__(64) void fin_kernel(const double* __restrict__ lsum,
                                                 float* __restrict__ out) {
    if (threadIdx.x == 0) {
        const float m = (float)(*lsum / (double)QELEMS);   // mean((q-x)^2)
        out[0] = m + m;                                    // vq_loss + commit_loss
    }
}

extern "C" void kernel_launch(void* const* d_in, const int* in_sizes, int n_in,
                              void* d_out, int out_size, void* d_ws, size_t ws_size,
                              hipStream_t stream) {
    const float* x = (const float*)d_in[0];
    const float* w = (const float*)d_in[1];
    float* out  = (float*)d_out;
    double* lsum = (double*)d_ws;
    float* w2   = (float*)((char*)d_ws + 16);
    unsigned short* wbf = (unsigned short*)((char*)d_ws + 2064);   // 16B-aligned, 256 KiB

    hipMemsetAsync(d_ws, 0, 16, stream);
    hipLaunchKernelGGL(prep_kernel, dim3(Kn), dim3(64), 0, stream, w, w2, wbf);
    hipLaunchKernelGGL(vq_main, dim3((int)(NROWS / BN)), dim3(256), 0, stream,
                       x, w, w2, wbf, out, lsum);
    hipLaunchKernelGGL(fin_kernel, dim3(1), dim3(1), 0, stream, lsum, out);
}